// Round 1
// baseline (198.827 us; speedup 1.0000x reference)
//
#include <hip/hip_runtime.h>
#include <math.h>

#define NATOM   32
#define NSP     4
#define NPAIRS  (NATOM * (NATOM - 1) / 2)   // 496
#define NCLS    10
#define NSHFR   16
#define NSHFA   4
#define NSHFZ   8
#define FEAT_ANG (NSHFA * NSHFZ)            // 32
#define OUT_PER_ATOM (NSP * NSHFR + NCLS * FEAT_ANG)  // 64 + 320 = 384

#define RCR_F 5.2f
#define RCA_F 3.5f
#define PI_F  3.14159265358979323846f

__global__ __launch_bounds__(64) void aev_kernel(
    const float* __restrict__ coords,   // (B, 32, 3)
    const float* __restrict__ etaR,     // (1,)
    const float* __restrict__ shfR,     // (16,)
    const float* __restrict__ etaA,     // (1,)
    const float* __restrict__ zeta,     // (1,)
    const float* __restrict__ shfA,     // (4,)
    const float* __restrict__ shfZ,     // (8,)
    const int*   __restrict__ species,  // (B, 32)
    float* __restrict__ out)            // (B, 32, 384)
{
    const int atom = blockIdx.x;        // b*32 + i
    const int b    = atom >> 5;
    const int i    = atom & 31;
    const int tid  = threadIdx.x;       // 0..63, single wave

    __shared__ float svx[NATOM], svy[NATOM], svz[NATOM];
    __shared__ float sd[NATOM], sfcA[NATOM], sfcR[NATOM];
    __shared__ int   ssp[NATOM];
    __shared__ float pc_c[NPAIRS], pc_s[NPAIRS], pc_dm[NPAIRS], pc_f[NPAIRS];
    __shared__ int   pc_cls[NPAIRS];

    // ---- center atom ----
    const float cix = coords[(b * NATOM + i) * 3 + 0];
    const float ciy = coords[(b * NATOM + i) * 3 + 1];
    const float ciz = coords[(b * NATOM + i) * 3 + 2];
    const int   spi = species[b * NATOM + i];

    // ---- phase 1: per-neighbor precompute (threads 0..31) ----
    if (tid < NATOM) {
        const int j = tid;
        const float x = coords[(b * NATOM + j) * 3 + 0];
        const float y = coords[(b * NATOM + j) * 3 + 1];
        const float z = coords[(b * NATOM + j) * 3 + 2];
        const float vx = x - cix, vy = y - ciy, vz = z - ciz;
        const float d2 = vx * vx + vy * vy + vz * vz;
        const float d  = sqrtf(d2 > 0.f ? d2 : 1.f);   // matches where(d2>0,d2,1)
        const int spj = species[b * NATOM + j];
        const bool ok = (j != i) && (spj >= 0) && (spi >= 0);
        // fold cutoff+validity masks into the cutoff functions
        const float fcA = (ok && d <= RCA_F) ? (0.5f * __cosf(d * (PI_F / RCA_F)) + 0.5f) : 0.f;
        const float fcR = (ok && d <= RCR_F) ? (0.5f * __cosf(d * (PI_F / RCR_F)) + 0.5f) : 0.f;
        svx[j] = vx; svy[j] = vy; svz[j] = vz;
        sd[j] = d; sfcA[j] = fcA; sfcR[j] = fcR;
        ssp[j] = spj < 0 ? 0 : (spj > (NSP - 1) ? (NSP - 1) : spj);
    }
    __syncthreads();

    const long obase = (long)atom * OUT_PER_ATOM;

    // ---- phase 2: radial. thread = (r = tid&15, jgroup = tid>>4) ----
    {
        const int r  = tid & 15;
        const int jg = tid >> 4;                 // 0..3
        const float shf = shfR[r];
        const float eta = etaR[0];
        float a0 = 0.f, a1 = 0.f, a2 = 0.f, a3 = 0.f;
        for (int j = jg; j < NATOM; j += 4) {
            const float fc = sfcR[j];
            if (fc > 0.f) {
                const float dd = sd[j] - shf;
                const float v = 0.25f * __expf(-eta * dd * dd) * fc;
                const int s = ssp[j];
                a0 += (s == 0) ? v : 0.f;
                a1 += (s == 1) ? v : 0.f;
                a2 += (s == 2) ? v : 0.f;
                a3 += (s == 3) ? v : 0.f;
            }
        }
        // reduce over jg (lanes differing in bits 4 and 5)
        a0 += __shfl_xor(a0, 16); a0 += __shfl_xor(a0, 32);
        a1 += __shfl_xor(a1, 16); a1 += __shfl_xor(a1, 32);
        a2 += __shfl_xor(a2, 16); a2 += __shfl_xor(a2, 32);
        a3 += __shfl_xor(a3, 16); a3 += __shfl_xor(a3, 32);
        if (tid < 16) {
            out[obase + 0 * NSHFR + r] = a0;
            out[obase + 1 * NSHFR + r] = a1;
            out[obase + 2 * NSHFR + r] = a2;
            out[obase + 3 * NSHFR + r] = a3;
        }
    }

    // ---- phase 3: pair build + deterministic ballot compaction ----
    int np = 0;
    for (int base_pid = 0; base_pid < NPAIRS; base_pid += 64) {
        const int pid = base_pid + tid;
        bool active = false;
        float c = 0.f, s = 0.f, dm = 0.f, fac = 0.f;
        int cls = 0;
        if (pid < NPAIRS) {
            // decode pid -> (j, k), j < k
            int j = 0, rem = pid;
            while (rem >= (NATOM - 1 - j)) { rem -= (NATOM - 1 - j); ++j; }
            const int k = j + 1 + rem;
            fac = 2.f * sfcA[j] * sfcA[k];       // masks folded into fcA
            if (fac > 0.f) {
                active = true;
                const float dj = sd[j], dk = sd[k];
                const float dot = svx[j] * svx[k] + svy[j] * svy[k] + svz[j] * svz[k];
                c = 0.95f * dot / fmaxf(dj * dk, 1e-10f);        // = cos(ang)
                s = sqrtf(fmaxf(1.f - c * c, 0.f));              // = sin(ang)
                dm = 0.5f * (dj + dk);
                const int sj = ssp[j], sk = ssp[k];
                const int lo = min(sj, sk), hi = max(sj, sk);
                cls = lo * NSP - ((lo * (lo - 1)) >> 1) + (hi - lo);  // triu index
            }
        }
        const unsigned long long m = __ballot(active);
        if (active) {
            const int pos = np + (int)__popcll(m & ((1ull << tid) - 1ull));
            pc_c[pos] = c; pc_s[pos] = s; pc_dm[pos] = dm; pc_f[pos] = fac;
            pc_cls[pos] = cls;
        }
        np += (int)__popcll(m);
    }
    __syncthreads();

    // ---- phase 4: angular. thread = (feature f = tid&31, half = tid>>5) ----
    {
        const int f = tid & 31;
        const int p = f >> 3;      // ShfA index
        const int t = f & 7;       // ShfZ index
        const int half = tid >> 5;
        float st, ct;
        __sincosf(shfZ[t], &st, &ct);
        const float sa = shfA[p];
        const float eA = etaA[0];
        const float zt = zeta[0];
        float acc[NCLS];
#pragma unroll
        for (int q = 0; q < NCLS; ++q) acc[q] = 0.f;

        for (int pp = half; pp < np; pp += 2) {
            const float c   = pc_c[pp];
            const float s   = pc_s[pp];
            const float fac = pc_f[pp];
            const float dmv = pc_dm[pp];
            const int   cls = pc_cls[pp];
            // cos(ang - ShfZ[t]) = c*cos + s*sin   (no arccos needed)
            float u = 0.5f + 0.5f * (c * ct + s * st);
            u = fmaxf(u, 0.f);
            const float f1 = __powf(u, zt);
            const float dd = dmv - sa;
            const float v = fac * f1 * __expf(-eA * dd * dd);
#pragma unroll
            for (int q = 0; q < NCLS; ++q)
                acc[q] += (cls == q) ? v : 0.f;
        }
#pragma unroll
        for (int q = 0; q < NCLS; ++q) acc[q] += __shfl_xor(acc[q], 32);
        if (tid < 32) {
            float* o = out + obase + NSP * NSHFR;
#pragma unroll
            for (int q = 0; q < NCLS; ++q) o[q * FEAT_ANG + f] = acc[q];
        }
    }
}

extern "C" void kernel_launch(void* const* d_in, const int* in_sizes, int n_in,
                              void* d_out, int out_size, void* d_ws, size_t ws_size,
                              hipStream_t stream) {
    const float* coords  = (const float*)d_in[0];
    const float* etaR    = (const float*)d_in[1];
    const float* shfR    = (const float*)d_in[2];
    const float* etaA    = (const float*)d_in[3];
    const float* zeta    = (const float*)d_in[4];
    const float* shfA    = (const float*)d_in[5];
    const float* shfZ    = (const float*)d_in[6];
    const int*   species = (const int*)d_in[7];
    float* out = (float*)d_out;

    const int B = in_sizes[0] / (NATOM * 3);
    aev_kernel<<<B * NATOM, 64, 0, stream>>>(coords, etaR, shfR, etaA, zeta,
                                             shfA, shfZ, species, out);
}

// Round 2
// 108.960 us; speedup vs baseline: 1.8248x; 1.8248x over previous
//
#include <hip/hip_runtime.h>
#include <math.h>

#define NATOM   32
#define NSP     4
#define NPAIRS  (NATOM * (NATOM - 1) / 2)   // 496
#define NCLS    10
#define NSHFR   16
#define NSHFA   4
#define NSHFZ   8
#define FEAT_ANG (NSHFA * NSHFZ)            // 32
#define OUT_PER_ATOM (NSP * NSHFR + NCLS * FEAT_ANG)  // 384

#define RCR_F 5.2f
#define RCA_F 3.5f
#define PI_F  3.14159265358979323846f

// angular accumulation over one class segment; FAST => zeta == 32 (5 squarings)
template <bool FAST>
__device__ __forceinline__ void angular_accum(
    const float2* __restrict__ pc_cs, const float* __restrict__ pc_ef,
    int s0, int e0, int half, int p, float ct, float st, float zt, float& acc)
{
    for (int pp = s0 + half; pp < e0; pp += 2) {
        const float2 cs = pc_cs[pp];
        const float  ee = pc_ef[pp * 4 + p];
        // u = 0.5 + 0.5*cos(ang - ShfZ[t]);  cs holds (0.5*cos(ang), 0.5*sin(ang))
        const float u = fmaf(cs.x, ct, fmaf(cs.y, st, 0.5f));
        float f1;
        if (FAST) {
            const float u2 = u * u, u4 = u2 * u2, u8 = u4 * u4, u16 = u8 * u8;
            f1 = u16 * u16;                       // u^32, u in [0,1]
        } else {
            f1 = __powf(fmaxf(u, 0.f), zt);
        }
        acc = fmaf(f1, ee, acc);
    }
}

__global__ __launch_bounds__(64) void aev_kernel(
    const float* __restrict__ coords,   // (B, 32, 3)
    const float* __restrict__ etaR,     // (1,)
    const float* __restrict__ shfR,     // (16,)
    const float* __restrict__ etaA,     // (1,)
    const float* __restrict__ zeta,     // (1,)
    const float* __restrict__ shfA,     // (4,)
    const float* __restrict__ shfZ,     // (8,)
    const int*   __restrict__ species,  // (B, 32)
    float* __restrict__ out)            // (B, 32, 384)
{
    const int atom = blockIdx.x;        // b*32 + i
    const int b    = atom >> 5;
    const int i    = atom & 31;
    const int tid  = threadIdx.x;       // 0..63, single wave

    __shared__ float svx[NATOM], svy[NATOM], svz[NATOM];
    __shared__ float sd[NATOM], sfcA[NATOM], sfcR[NATOM];
    __shared__ int   ssp[NATOM];
    __shared__ float2 pc_cs[NPAIRS];    // (0.5*cos, 0.5*sin) per pair, class-sorted
    __shared__ float4 pc_e[NPAIRS];     // fac*exp(-etaA*(dm-ShfA[p])^2), p=0..3

    const float cix = coords[(b * NATOM + i) * 3 + 0];
    const float ciy = coords[(b * NATOM + i) * 3 + 1];
    const float ciz = coords[(b * NATOM + i) * 3 + 2];
    const int   spi = species[b * NATOM + i];

    // ---- phase 1: per-neighbor precompute (threads 0..31) ----
    if (tid < NATOM) {
        const int j = tid;
        const float x = coords[(b * NATOM + j) * 3 + 0];
        const float y = coords[(b * NATOM + j) * 3 + 1];
        const float z = coords[(b * NATOM + j) * 3 + 2];
        const float vx = x - cix, vy = y - ciy, vz = z - ciz;
        const float d2 = vx * vx + vy * vy + vz * vz;
        const float d  = sqrtf(d2 > 0.f ? d2 : 1.f);
        const int spj = species[b * NATOM + j];
        const bool ok = (j != i) && (spj >= 0) && (spi >= 0);
        const float fcA = (ok && d <= RCA_F) ? (0.5f * __cosf(d * (PI_F / RCA_F)) + 0.5f) : 0.f;
        const float fcR = (ok && d <= RCR_F) ? (0.5f * __cosf(d * (PI_F / RCR_F)) + 0.5f) : 0.f;
        svx[j] = vx; svy[j] = vy; svz[j] = vz;
        sd[j] = d; sfcA[j] = fcA; sfcR[j] = fcR;
        ssp[j] = spj < 0 ? 0 : (spj > (NSP - 1) ? (NSP - 1) : spj);
    }
    __syncthreads();

    const long obase = (long)atom * OUT_PER_ATOM;

    // ---- phase 2: radial. thread = (r = tid&15, jgroup = tid>>4) ----
    {
        const int r  = tid & 15;
        const int jg = tid >> 4;
        const float shf = shfR[r];
        const float eta = etaR[0];
        float a0 = 0.f, a1 = 0.f, a2 = 0.f, a3 = 0.f;
        for (int j = jg; j < NATOM; j += 4) {
            const float fc = sfcR[j];
            if (fc > 0.f) {
                const float dd = sd[j] - shf;
                const float v = 0.25f * __expf(-eta * dd * dd) * fc;
                const int s = ssp[j];
                a0 += (s == 0) ? v : 0.f;
                a1 += (s == 1) ? v : 0.f;
                a2 += (s == 2) ? v : 0.f;
                a3 += (s == 3) ? v : 0.f;
            }
        }
        a0 += __shfl_xor(a0, 16); a0 += __shfl_xor(a0, 32);
        a1 += __shfl_xor(a1, 16); a1 += __shfl_xor(a1, 32);
        a2 += __shfl_xor(a2, 16); a2 += __shfl_xor(a2, 32);
        a3 += __shfl_xor(a3, 16); a3 += __shfl_xor(a3, 32);
        if (tid < 16) {
            out[obase + 0 * NSHFR + r] = a0;
            out[obase + 1 * NSHFR + r] = a1;
            out[obase + 2 * NSHFR + r] = a2;
            out[obase + 3 * NSHFR + r] = a3;
        }
    }

    // ---- phase 3A: count pairs per species-class (deterministic ballots) ----
    const unsigned long long ltmask = (tid == 0) ? 0ull : ((~0ull) >> (64 - tid));
    int cache_w[8];        // j | k<<8 | cls<<16 | act<<24
    float cache_fac[8];
    int cnt[NCLS];
#pragma unroll
    for (int q = 0; q < NCLS; ++q) cnt[q] = 0;

#pragma unroll
    for (int cc = 0; cc < 8; ++cc) {
        const int pid = cc * 64 + tid;
        bool act = false; int j = 0, k = 0, cls = 0; float fac = 0.f;
        if (pid < NPAIRS) {
            // closed-form decode pid -> (j,k), j<k ; S(j) = 31j - j(j-1)/2
            j = (int)((63.0f - sqrtf((float)(3969 - 8 * pid))) * 0.5f);
            int Sj = j * 31 - ((j * (j - 1)) >> 1);
            if (Sj > pid) { --j; Sj = j * 31 - ((j * (j - 1)) >> 1); }
            else {
                const int Sn = (j + 1) * 31 - (((j + 1) * j) >> 1);
                if (Sn <= pid) { j += 1; Sj = Sn; }
            }
            k = j + 1 + (pid - Sj);
            fac = 2.f * sfcA[j] * sfcA[k];
            if (fac > 0.f) {
                act = true;
                const int sj = ssp[j], sk = ssp[k];
                const int lo = min(sj, sk), hi = max(sj, sk);
                cls = lo * NSP - ((lo * (lo - 1)) >> 1) + (hi - lo);
            }
        }
        cache_w[cc] = j | (k << 8) | (cls << 16) | (act ? (1 << 24) : 0);
        cache_fac[cc] = fac;
#pragma unroll
        for (int q = 0; q < NCLS; ++q)
            cnt[q] += (int)__popcll(__ballot(act && cls == q));
    }

    int off[NCLS], wp[NCLS];
    {
        int run = 0;
#pragma unroll
        for (int q = 0; q < NCLS; ++q) { off[q] = run; wp[q] = run; run += cnt[q]; }
    }

    // ---- phase 3B: place pairs class-sorted; precompute cs + exp factors ----
    const float eA  = etaA[0];
    const float sa0 = shfA[0], sa1 = shfA[1], sa2 = shfA[2], sa3 = shfA[3];
#pragma unroll
    for (int cc = 0; cc < 8; ++cc) {
        const int w = cache_w[cc];
        const bool act = (w >> 24) != 0;
        const int j = w & 0xff, k = (w >> 8) & 0xff, cls = (w >> 16) & 0xff;
        const float fac = cache_fac[cc];
        float hc = 0.f, hs = 0.f, e0 = 0.f, e1 = 0.f, e2 = 0.f, e3 = 0.f;
        if (act) {
            const float dj = sd[j], dk = sd[k];
            const float dot = svx[j] * svx[k] + svy[j] * svy[k] + svz[j] * svz[k];
            const float c = 0.95f * dot * __builtin_amdgcn_rcpf(fmaxf(dj * dk, 1e-10f));
            const float s = __builtin_amdgcn_sqrtf(fmaxf(1.f - c * c, 0.f));
            hc = 0.5f * c; hs = 0.5f * s;
            const float dm = 0.5f * (dj + dk);
            const float d0 = dm - sa0, d1 = dm - sa1, d2 = dm - sa2, d3 = dm - sa3;
            e0 = fac * __expf(-eA * d0 * d0);
            e1 = fac * __expf(-eA * d1 * d1);
            e2 = fac * __expf(-eA * d2 * d2);
            e3 = fac * __expf(-eA * d3 * d3);
        }
#pragma unroll
        for (int q = 0; q < NCLS; ++q) {
            const unsigned long long m = __ballot(act && cls == q);
            if (act && cls == q) {
                const int pos = wp[q] + (int)__popcll(m & ltmask);
                pc_cs[pos] = make_float2(hc, hs);
                pc_e[pos]  = make_float4(e0, e1, e2, e3);
            }
            wp[q] += (int)__popcll(m);
        }
    }
    __syncthreads();

    // ---- phase 4: angular, class-sorted segments, one accumulator ----
    {
        const int f = tid & 31;
        const int p = f >> 3;       // ShfA index
        const int t = f & 7;        // ShfZ index
        const int half = tid >> 5;
        float st, ct;
        __sincosf(shfZ[t], &st, &ct);
        const float zt = zeta[0];
        const float* pc_ef = (const float*)pc_e;
        float* oang = out + obase + NSP * NSHFR;

        if (zt == 32.0f) {
#pragma unroll
            for (int q = 0; q < NCLS; ++q) {
                float acc = 0.f;
                angular_accum<true>(pc_cs, pc_ef, off[q], off[q] + cnt[q], half, p, ct, st, zt, acc);
                acc += __shfl_xor(acc, 32);
                if (tid < 32) oang[q * FEAT_ANG + f] = acc;
            }
        } else {
#pragma unroll
            for (int q = 0; q < NCLS; ++q) {
                float acc = 0.f;
                angular_accum<false>(pc_cs, pc_ef, off[q], off[q] + cnt[q], half, p, ct, st, zt, acc);
                acc += __shfl_xor(acc, 32);
                if (tid < 32) oang[q * FEAT_ANG + f] = acc;
            }
        }
    }
}

extern "C" void kernel_launch(void* const* d_in, const int* in_sizes, int n_in,
                              void* d_out, int out_size, void* d_ws, size_t ws_size,
                              hipStream_t stream) {
    const float* coords  = (const float*)d_in[0];
    const float* etaR    = (const float*)d_in[1];
    const float* shfR    = (const float*)d_in[2];
    const float* etaA    = (const float*)d_in[3];
    const float* zeta    = (const float*)d_in[4];
    const float* shfA    = (const float*)d_in[5];
    const float* shfZ    = (const float*)d_in[6];
    const int*   species = (const int*)d_in[7];
    float* out = (float*)d_out;

    const int B = in_sizes[0] / (NATOM * 3);
    aev_kernel<<<B * NATOM, 64, 0, stream>>>(coords, etaR, shfR, etaA, zeta,
                                             shfA, shfZ, species, out);
}

// Round 3
// 96.242 us; speedup vs baseline: 2.0659x; 1.1321x over previous
//
#include <hip/hip_runtime.h>
#include <math.h>

#define NATOM   32
#define NSP     4
#define NPAIRS  (NATOM * (NATOM - 1) / 2)   // 496
#define NCLS    10
#define NSHFR   16
#define NSHFA   4
#define NSHFZ   8
#define FEAT_ANG (NSHFA * NSHFZ)            // 32
#define OUT_PER_ATOM (NSP * NSHFR + NCLS * FEAT_ANG)  // 384

#define RCR_F 5.2f
#define RCA_F 3.5f
#define PI_F  3.14159265358979323846f

// angular accumulation over one class segment; FAST => zeta == 32 (5 squarings)
template <bool FAST>
__device__ __forceinline__ void angular_accum(
    const float2* __restrict__ pc_cs, const float* __restrict__ pc_ef,
    int s0, int e0, int p, float ct, float st, float zt, float& acc)
{
    for (int pp = s0; pp < e0; ++pp) {
        const float2 cs = pc_cs[pp];
        const float  ee = pc_ef[pp * 4 + p];
        // u = 0.5 + 0.5*cos(ang - ShfZ[t]);  cs holds (0.5*cos(ang), 0.5*sin(ang))
        const float u = fmaf(cs.x, ct, fmaf(cs.y, st, 0.5f));
        float f1;
        if (FAST) {
            const float u2 = u * u, u4 = u2 * u2, u8 = u4 * u4, u16 = u8 * u8;
            f1 = u16 * u16;                       // u^32, u in [0,1]
        } else {
            f1 = __powf(fmaxf(u, 0.f), zt);
        }
        acc = fmaf(f1, ee, acc);
    }
}

__global__ __launch_bounds__(64) void aev_kernel(
    const float* __restrict__ coords,   // (B, 32, 3)
    const float* __restrict__ etaR,     // (1,)
    const float* __restrict__ shfR,     // (16,)
    const float* __restrict__ etaA,     // (1,)
    const float* __restrict__ zeta,     // (1,)
    const float* __restrict__ shfA,     // (4,)
    const float* __restrict__ shfZ,     // (8,)
    const int*   __restrict__ species,  // (B, 32)
    float* __restrict__ out)            // (B, 32, 384)
{
    const int atom = blockIdx.x;        // b*32 + i
    const int b    = atom >> 5;
    const int i    = atom & 31;
    const int tid  = threadIdx.x;       // 0..63, single wave

    __shared__ float svx[NATOM], svy[NATOM], svz[NATOM];
    __shared__ float sd[NATOM], sfcA[NATOM], sfcR[NATOM];
    __shared__ int   ssp[NATOM];
    __shared__ float2 pc_cs[NPAIRS];    // (0.5*cos, 0.5*sin) per pair, class-sorted
    __shared__ float4 pc_e[NPAIRS];     // fac*exp(-etaA*(dm-ShfA[p])^2), p=0..3
    __shared__ int   s_cnt[NCLS];       // per-class pair counts
    __shared__ int   s_wp[NCLS];        // per-class write pointers

    const float cix = coords[(b * NATOM + i) * 3 + 0];
    const float ciy = coords[(b * NATOM + i) * 3 + 1];
    const float ciz = coords[(b * NATOM + i) * 3 + 2];
    const int   spi = species[b * NATOM + i];

    // ---- phase 1: per-neighbor precompute (threads 0..31) ----
    if (tid < NATOM) {
        const int j = tid;
        const float x = coords[(b * NATOM + j) * 3 + 0];
        const float y = coords[(b * NATOM + j) * 3 + 1];
        const float z = coords[(b * NATOM + j) * 3 + 2];
        const float vx = x - cix, vy = y - ciy, vz = z - ciz;
        const float d2 = vx * vx + vy * vy + vz * vz;
        const float d  = sqrtf(d2 > 0.f ? d2 : 1.f);
        const int spj = species[b * NATOM + j];
        const bool ok = (j != i) && (spj >= 0) && (spi >= 0);
        const float fcA = (ok && d <= RCA_F) ? (0.5f * __cosf(d * (PI_F / RCA_F)) + 0.5f) : 0.f;
        const float fcR = (ok && d <= RCR_F) ? (0.5f * __cosf(d * (PI_F / RCR_F)) + 0.5f) : 0.f;
        svx[j] = vx; svy[j] = vy; svz[j] = vz;
        sd[j] = d; sfcA[j] = fcA; sfcR[j] = fcR;
        ssp[j] = spj < 0 ? 0 : (spj > (NSP - 1) ? (NSP - 1) : spj);
    }
    if (tid < NCLS) s_cnt[tid] = 0;
    __syncthreads();

    const long obase = (long)atom * OUT_PER_ATOM;

    // ---- phase 2: radial. thread = (r = tid&15, jgroup = tid>>4) ----
    {
        const int r  = tid & 15;
        const int jg = tid >> 4;
        const float shf = shfR[r];
        const float eta = etaR[0];
        float a0 = 0.f, a1 = 0.f, a2 = 0.f, a3 = 0.f;
        for (int j = jg; j < NATOM; j += 4) {
            const float fc = sfcR[j];
            if (fc > 0.f) {
                const float dd = sd[j] - shf;
                const float v = 0.25f * __expf(-eta * dd * dd) * fc;
                const int s = ssp[j];
                a0 += (s == 0) ? v : 0.f;
                a1 += (s == 1) ? v : 0.f;
                a2 += (s == 2) ? v : 0.f;
                a3 += (s == 3) ? v : 0.f;
            }
        }
        a0 += __shfl_xor(a0, 16); a0 += __shfl_xor(a0, 32);
        a1 += __shfl_xor(a1, 16); a1 += __shfl_xor(a1, 32);
        a2 += __shfl_xor(a2, 16); a2 += __shfl_xor(a2, 32);
        a3 += __shfl_xor(a3, 16); a3 += __shfl_xor(a3, 32);
        if (tid < 16) {
            out[obase + 0 * NSHFR + r] = a0;
            out[obase + 1 * NSHFR + r] = a1;
            out[obase + 2 * NSHFR + r] = a2;
            out[obase + 3 * NSHFR + r] = a3;
        }
    }

    // ---- phase 3A: decode pairs, count per species-class via LDS atomics ----
    int   cache_w[8];      // j | k<<8 | cls<<16 | act<<24
    float cache_fac[8];

#pragma unroll
    for (int cc = 0; cc < 8; ++cc) {
        const int pid = cc * 64 + tid;
        bool act = false; int j = 0, k = 0, cls = 0; float fac = 0.f;
        if (pid < NPAIRS) {
            // closed-form decode pid -> (j,k), j<k ; S(j) = 31j - j(j-1)/2
            j = (int)((63.0f - sqrtf((float)(3969 - 8 * pid))) * 0.5f);
            int Sj = j * 31 - ((j * (j - 1)) >> 1);
            if (Sj > pid) { --j; Sj = j * 31 - ((j * (j - 1)) >> 1); }
            else {
                const int Sn = (j + 1) * 31 - (((j + 1) * j) >> 1);
                if (Sn <= pid) { j += 1; Sj = Sn; }
            }
            k = j + 1 + (pid - Sj);
            fac = 2.f * sfcA[j] * sfcA[k];
            if (fac > 0.f) {
                act = true;
                const int sj = ssp[j], sk = ssp[k];
                const int lo = min(sj, sk), hi = max(sj, sk);
                cls = lo * NSP - ((lo * (lo - 1)) >> 1) + (hi - lo);
                atomicAdd(&s_cnt[cls], 1);
            }
        }
        cache_w[cc] = j | (k << 8) | (cls << 16) | (act ? (1 << 24) : 0);
        cache_fac[cc] = fac;
    }
    __syncthreads();

    // ---- offsets: every lane computes the same prefix over 10 counters ----
    int off[NCLS], cntv[NCLS];
    {
        int run = 0;
#pragma unroll
        for (int q = 0; q < NCLS; ++q) { cntv[q] = s_cnt[q]; off[q] = run; run += cntv[q]; }
    }
    if (tid < NCLS) s_wp[tid] = off[tid];
    __syncthreads();

    // ---- phase 3B: place pairs class-sorted; precompute cs + exp factors ----
    const float eA  = etaA[0];
    const float sa0 = shfA[0], sa1 = shfA[1], sa2 = shfA[2], sa3 = shfA[3];
#pragma unroll
    for (int cc = 0; cc < 8; ++cc) {
        const int w = cache_w[cc];
        if ((w >> 24) != 0) {
            const int j = w & 0xff, k = (w >> 8) & 0xff, cls = (w >> 16) & 0xff;
            const float fac = cache_fac[cc];
            const float dj = sd[j], dk = sd[k];
            const float dot = svx[j] * svx[k] + svy[j] * svy[k] + svz[j] * svz[k];
            const float c = 0.95f * dot * __builtin_amdgcn_rcpf(fmaxf(dj * dk, 1e-10f));
            const float s = __builtin_amdgcn_sqrtf(fmaxf(1.f - c * c, 0.f));
            const float dm = 0.5f * (dj + dk);
            const float d0 = dm - sa0, d1 = dm - sa1, d2 = dm - sa2, d3 = dm - sa3;
            const float e0 = fac * __expf(-eA * d0 * d0);
            const float e1 = fac * __expf(-eA * d1 * d1);
            const float e2 = fac * __expf(-eA * d2 * d2);
            const float e3 = fac * __expf(-eA * d3 * d3);
            const int pos = atomicAdd(&s_wp[cls], 1);
            pc_cs[pos] = make_float2(0.5f * c, 0.5f * s);
            pc_e[pos]  = make_float4(e0, e1, e2, e3);
        }
    }
    __syncthreads();

    // ---- phase 4: angular. half 0 -> classes {0,2,4,6,8}, half 1 -> odd ----
    {
        const int f = tid & 31;
        const int p = f >> 3;       // ShfA index
        const int t = f & 7;        // ShfZ index
        const int half = tid >> 5;
        float st, ct;
        __sincosf(shfZ[t], &st, &ct);
        const float zt = zeta[0];
        const float* pc_ef = (const float*)pc_e;
        float* oang = out + obase + NSP * NSHFR;

        if (zt == 32.0f) {
#pragma unroll
            for (int qi = 0; qi < NCLS / 2; ++qi) {
                const int q = qi * 2 + half;
                float acc = 0.f;
                angular_accum<true>(pc_cs, pc_ef, off[q], off[q] + cntv[q], p, ct, st, zt, acc);
                oang[q * FEAT_ANG + f] = acc;
            }
        } else {
#pragma unroll
            for (int qi = 0; qi < NCLS / 2; ++qi) {
                const int q = qi * 2 + half;
                float acc = 0.f;
                angular_accum<false>(pc_cs, pc_ef, off[q], off[q] + cntv[q], p, ct, st, zt, acc);
                oang[q * FEAT_ANG + f] = acc;
            }
        }
    }
}

extern "C" void kernel_launch(void* const* d_in, const int* in_sizes, int n_in,
                              void* d_out, int out_size, void* d_ws, size_t ws_size,
                              hipStream_t stream) {
    const float* coords  = (const float*)d_in[0];
    const float* etaR    = (const float*)d_in[1];
    const float* shfR    = (const float*)d_in[2];
    const float* etaA    = (const float*)d_in[3];
    const float* zeta    = (const float*)d_in[4];
    const float* shfA    = (const float*)d_in[5];
    const float* shfZ    = (const float*)d_in[6];
    const int*   species = (const int*)d_in[7];
    float* out = (float*)d_out;

    const int B = in_sizes[0] / (NATOM * 3);
    aev_kernel<<<B * NATOM, 64, 0, stream>>>(coords, etaR, shfR, etaA, zeta,
                                             shfA, shfZ, species, out);
}

// Round 4
// 89.537 us; speedup vs baseline: 2.2206x; 1.0749x over previous
//
#include <hip/hip_runtime.h>
#include <math.h>

#define NATOM   32
#define NSP     4
#define NPAIRS  (NATOM * (NATOM - 1) / 2)   // 496
#define NCLS    10
#define NSHFR   16
#define NSHFA   4
#define NSHFZ   8
#define FEAT_ANG (NSHFA * NSHFZ)            // 32
#define OUT_PER_ATOM (NSP * NSHFR + NCLS * FEAT_ANG)  // 384

#define RCR_F 5.2f
#define RCA_F 3.5f
#define PI_F  3.14159265358979323846f

// angular accumulation over one class segment; FAST => zeta == 32 (5 squarings)
template <bool FAST>
__device__ __forceinline__ void angular_accum(
    const float2* __restrict__ pc_cs, const float* __restrict__ pc_ef,
    int s0, int e0, int p, float ct, float st, float zt, float& acc)
{
    for (int pp = s0; pp < e0; ++pp) {
        const float2 cs = pc_cs[pp];
        const float  ee = pc_ef[pp * 4 + p];
        // u = 0.5 + 0.5*cos(ang - ShfZ[t]);  cs holds (0.5*cos(ang), 0.5*sin(ang))
        const float u = fmaf(cs.x, ct, fmaf(cs.y, st, 0.5f));
        float f1;
        if (FAST) {
            const float u2 = u * u, u4 = u2 * u2, u8 = u4 * u4, u16 = u8 * u8;
            f1 = u16 * u16;                       // u^32, u in [0,1]
        } else {
            f1 = __powf(fmaxf(u, 0.f), zt);
        }
        acc = fmaf(f1, ee, acc);
    }
}

// class stripes across the 4 (wave, half) lane groups, balanced by expected
// class weight (species ~ U{0..3}): {0,1,4}=4/16, {2,3}=4/16, {5,6}=4/16,
// {7,8,9}=4/16
__device__ __constant__ int STRIPE_CLS[4][3] = {
    {0, 1, 4}, {2, 3, -1}, {5, 6, -1}, {7, 8, 9}
};

__global__ __launch_bounds__(128) void aev_kernel(
    const float* __restrict__ coords,   // (B, 32, 3)
    const float* __restrict__ etaR,     // (1,)
    const float* __restrict__ shfR,     // (16,)
    const float* __restrict__ etaA,     // (1,)
    const float* __restrict__ zeta,     // (1,)
    const float* __restrict__ shfA,     // (4,)
    const float* __restrict__ shfZ,     // (8,)
    const int*   __restrict__ species,  // (B, 32)
    float* __restrict__ out)            // (B, 32, 384)
{
    const int atom = blockIdx.x;        // b*32 + i
    const int b    = atom >> 5;
    const int i    = atom & 31;
    const int tid  = threadIdx.x;       // 0..127, two waves

    __shared__ float svx[NATOM], svy[NATOM], svz[NATOM];
    __shared__ float sd[NATOM], sfcA[NATOM], sfcR[NATOM];
    __shared__ int   ssp[NATOM];
    __shared__ float2 pc_cs[NPAIRS];    // (0.5*cos, 0.5*sin), class-sorted
    __shared__ float4 pc_e[NPAIRS];     // fac*exp(-etaA*(dm-ShfA[p])^2), p=0..3
    __shared__ int   s_cnt[NCLS];
    __shared__ int   s_wp[NCLS];

    const float cix = coords[(b * NATOM + i) * 3 + 0];
    const float ciy = coords[(b * NATOM + i) * 3 + 1];
    const float ciz = coords[(b * NATOM + i) * 3 + 2];
    const int   spi = species[b * NATOM + i];

    // ---- phase 1: per-neighbor precompute (threads 0..31) ----
    if (tid < NATOM) {
        const int j = tid;
        const float x = coords[(b * NATOM + j) * 3 + 0];
        const float y = coords[(b * NATOM + j) * 3 + 1];
        const float z = coords[(b * NATOM + j) * 3 + 2];
        const float vx = x - cix, vy = y - ciy, vz = z - ciz;
        const float d2 = vx * vx + vy * vy + vz * vz;
        const float d  = sqrtf(d2 > 0.f ? d2 : 1.f);
        const int spj = species[b * NATOM + j];
        const bool ok = (j != i) && (spj >= 0) && (spi >= 0);
        const float fcA = (ok && d <= RCA_F) ? (0.5f * __cosf(d * (PI_F / RCA_F)) + 0.5f) : 0.f;
        const float fcR = (ok && d <= RCR_F) ? (0.5f * __cosf(d * (PI_F / RCR_F)) + 0.5f) : 0.f;
        svx[j] = vx; svy[j] = vy; svz[j] = vz;
        sd[j] = d; sfcA[j] = fcA; sfcR[j] = fcR;
        ssp[j] = spj < 0 ? 0 : (spj > (NSP - 1) ? (NSP - 1) : spj);
    }
    if (tid < NCLS) s_cnt[tid] = 0;
    __syncthreads();

    const long obase = (long)atom * OUT_PER_ATOM;

    // ---- phase 2: radial (wave 0 only). thread = (r = tid&15, jg = tid>>4) ----
    if (tid < 64) {
        const int r  = tid & 15;
        const int jg = tid >> 4;
        const float shf = shfR[r];
        const float eta = etaR[0];
        float a0 = 0.f, a1 = 0.f, a2 = 0.f, a3 = 0.f;
        for (int j = jg; j < NATOM; j += 4) {
            const float fc = sfcR[j];
            if (fc > 0.f) {
                const float dd = sd[j] - shf;
                const float v = 0.25f * __expf(-eta * dd * dd) * fc;
                const int s = ssp[j];
                a0 += (s == 0) ? v : 0.f;
                a1 += (s == 1) ? v : 0.f;
                a2 += (s == 2) ? v : 0.f;
                a3 += (s == 3) ? v : 0.f;
            }
        }
        a0 += __shfl_xor(a0, 16); a0 += __shfl_xor(a0, 32);
        a1 += __shfl_xor(a1, 16); a1 += __shfl_xor(a1, 32);
        a2 += __shfl_xor(a2, 16); a2 += __shfl_xor(a2, 32);
        a3 += __shfl_xor(a3, 16); a3 += __shfl_xor(a3, 32);
        if (tid < 16) {
            out[obase + 0 * NSHFR + r] = a0;
            out[obase + 1 * NSHFR + r] = a1;
            out[obase + 2 * NSHFR + r] = a2;
            out[obase + 3 * NSHFR + r] = a3;
        }
    }

    // ---- phase 3A: decode pairs, count per class via LDS atomics (both waves) ----
    int   cache_w[4];      // j | k<<8 | cls<<16 | act<<24
    float cache_fac[4];

#pragma unroll
    for (int cc = 0; cc < 4; ++cc) {
        const int pid = cc * 128 + tid;
        bool act = false; int j = 0, k = 0, cls = 0; float fac = 0.f;
        if (pid < NPAIRS) {
            // closed-form decode pid -> (j,k), j<k ; S(j) = 31j - j(j-1)/2
            j = (int)((63.0f - sqrtf((float)(3969 - 8 * pid))) * 0.5f);
            int Sj = j * 31 - ((j * (j - 1)) >> 1);
            if (Sj > pid) { --j; Sj = j * 31 - ((j * (j - 1)) >> 1); }
            else {
                const int Sn = (j + 1) * 31 - (((j + 1) * j) >> 1);
                if (Sn <= pid) { j += 1; Sj = Sn; }
            }
            k = j + 1 + (pid - Sj);
            fac = 2.f * sfcA[j] * sfcA[k];
            if (fac > 0.f) {
                act = true;
                const int sj = ssp[j], sk = ssp[k];
                const int lo = min(sj, sk), hi = max(sj, sk);
                cls = lo * NSP - ((lo * (lo - 1)) >> 1) + (hi - lo);
                atomicAdd(&s_cnt[cls], 1);
            }
        }
        cache_w[cc] = j | (k << 8) | (cls << 16) | (act ? (1 << 24) : 0);
        cache_fac[cc] = fac;
    }
    __syncthreads();

    // ---- offsets: every lane computes the same prefix over 10 counters ----
    int off[NCLS], cntv[NCLS];
    {
        int run = 0;
#pragma unroll
        for (int q = 0; q < NCLS; ++q) { cntv[q] = s_cnt[q]; off[q] = run; run += cntv[q]; }
    }
    if (tid < NCLS) s_wp[tid] = off[tid];
    __syncthreads();

    // ---- phase 3B: place pairs class-sorted; precompute cs + exp factors ----
    const float eA  = etaA[0];
    const float sa0 = shfA[0], sa1 = shfA[1], sa2 = shfA[2], sa3 = shfA[3];
#pragma unroll
    for (int cc = 0; cc < 4; ++cc) {
        const int w = cache_w[cc];
        if ((w >> 24) != 0) {
            const int j = w & 0xff, k = (w >> 8) & 0xff, cls = (w >> 16) & 0xff;
            const float fac = cache_fac[cc];
            const float dj = sd[j], dk = sd[k];
            const float dot = svx[j] * svx[k] + svy[j] * svy[k] + svz[j] * svz[k];
            const float c = 0.95f * dot * __builtin_amdgcn_rcpf(fmaxf(dj * dk, 1e-10f));
            const float s = __builtin_amdgcn_sqrtf(fmaxf(1.f - c * c, 0.f));
            const float dm = 0.5f * (dj + dk);
            const float d0 = dm - sa0, d1 = dm - sa1, d2 = dm - sa2, d3 = dm - sa3;
            const float e0 = fac * __expf(-eA * d0 * d0);
            const float e1 = fac * __expf(-eA * d1 * d1);
            const float e2 = fac * __expf(-eA * d2 * d2);
            const float e3 = fac * __expf(-eA * d3 * d3);
            const int pos = atomicAdd(&s_wp[cls], 1);
            pc_cs[pos] = make_float2(0.5f * c, 0.5f * s);
            pc_e[pos]  = make_float4(e0, e1, e2, e3);
        }
    }
    __syncthreads();

    // ---- phase 4: angular. 4 lane-groups own disjoint class stripes ----
    {
        const int f = tid & 31;
        const int p = f >> 3;       // ShfA index
        const int t = f & 7;        // ShfZ index
        const int stripe = tid >> 5;  // 0..3 (wave, half)
        float st, ct;
        __sincosf(shfZ[t], &st, &ct);
        const float zt = zeta[0];
        const float* pc_ef = (const float*)pc_e;
        float* oang = out + obase + NSP * NSHFR;

        if (zt == 32.0f) {
#pragma unroll
            for (int s = 0; s < 3; ++s) {
                const int q = STRIPE_CLS[stripe][s];
                if (q >= 0) {
                    float acc = 0.f;
                    angular_accum<true>(pc_cs, pc_ef, off[q], off[q] + cntv[q], p, ct, st, zt, acc);
                    oang[q * FEAT_ANG + f] = acc;
                }
            }
        } else {
#pragma unroll
            for (int s = 0; s < 3; ++s) {
                const int q = STRIPE_CLS[stripe][s];
                if (q >= 0) {
                    float acc = 0.f;
                    angular_accum<false>(pc_cs, pc_ef, off[q], off[q] + cntv[q], p, ct, st, zt, acc);
                    oang[q * FEAT_ANG + f] = acc;
                }
            }
        }
    }
}

extern "C" void kernel_launch(void* const* d_in, const int* in_sizes, int n_in,
                              void* d_out, int out_size, void* d_ws, size_t ws_size,
                              hipStream_t stream) {
    const float* coords  = (const float*)d_in[0];
    const float* etaR    = (const float*)d_in[1];
    const float* shfR    = (const float*)d_in[2];
    const float* etaA    = (const float*)d_in[3];
    const float* zeta    = (const float*)d_in[4];
    const float* shfA    = (const float*)d_in[5];
    const float* shfZ    = (const float*)d_in[6];
    const int*   species = (const int*)d_in[7];
    float* out = (float*)d_out;

    const int B = in_sizes[0] / (NATOM * 3);
    aev_kernel<<<B * NATOM, 128, 0, stream>>>(coords, etaR, shfR, etaA, zeta,
                                              shfA, shfZ, species, out);
}

// Round 5
// 86.867 us; speedup vs baseline: 2.2889x; 1.0307x over previous
//
#include <hip/hip_runtime.h>
#include <hip/hip_fp16.h>
#include <math.h>

#define NATOM   32
#define NSP     4
#define NPAIRS  (NATOM * (NATOM - 1) / 2)   // 496
#define NCLS    10
#define NSHFR   16
#define NSHFA   4
#define NSHFZ   8
#define FEAT_ANG (NSHFA * NSHFZ)            // 32
#define OUT_PER_ATOM (NSP * NSHFR + NCLS * FEAT_ANG)  // 384

#define RCR_F 5.2f
#define RCA_F 3.5f
#define PI_F  3.14159265358979323846f

// angular accumulation over one class segment; FAST => zeta == 32 (5 squarings)
template <bool FAST>
__device__ __forceinline__ void angular_accum(
    const float2* __restrict__ pc_cs, const __half* __restrict__ pc_eh,
    int s0, int e0, int p, float ct, float st, float zt, float& acc)
{
    for (int pp = s0; pp < e0; ++pp) {
        const float2 cs = pc_cs[pp];
        const float  ee = __half2float(pc_eh[pp * 4 + p]);
        // u = 0.5 + 0.5*cos(ang - ShfZ[t]);  cs holds (0.5*cos, 0.5*sin)
        const float u = fmaf(cs.x, ct, fmaf(cs.y, st, 0.5f));
        float f1;
        if (FAST) {
            const float u2 = u * u, u4 = u2 * u2, u8 = u4 * u4, u16 = u8 * u8;
            f1 = u16 * u16;                       // u^32, u in [0,1]
        } else {
            f1 = __powf(fmaxf(u, 0.f), zt);
        }
        acc = fmaf(f1, ee, acc);
    }
}

// 8 stripes (32 lanes each) own disjoint classes, balanced by expected weight
// (species ~ U{0..3}): {1},{2},{3},{5},{6},{8},{0,4},{7,9} — each 2/16.
// Nibble tables: qa = primary class, qb = secondary (0xF = none).
#define STRIPE_TAB_A 0x70865321u
#define STRIPE_TAB_B 0x94FFFFFFu

__global__ __launch_bounds__(256, 8) void aev_kernel(
    const float* __restrict__ coords,   // (B, 32, 3)
    const float* __restrict__ etaR,     // (1,)
    const float* __restrict__ shfR,     // (16,)
    const float* __restrict__ etaA,     // (1,)
    const float* __restrict__ zeta,     // (1,)
    const float* __restrict__ shfA,     // (4,)
    const float* __restrict__ shfZ,     // (8,)
    const int*   __restrict__ species,  // (B, 32)
    float* __restrict__ out)            // (B, 32, 384)
{
    const int atom = blockIdx.x;        // b*32 + i
    const int b    = atom >> 5;
    const int i    = atom & 31;
    const int tid  = threadIdx.x;       // 0..255, four waves

    __shared__ float svx[NATOM], svy[NATOM], svz[NATOM];
    __shared__ float sd[NATOM], sfcA[NATOM], sfcR[NATOM];
    __shared__ int   ssp[NATOM];
    __shared__ float2 pc_cs[NPAIRS];                    // (0.5*cos, 0.5*sin)
    __shared__ __align__(8) __half pc_eh[NPAIRS * 4];   // fac*exp(...), p=0..3
    __shared__ int   s_cnt[NCLS];       // per-class pair counts
    __shared__ int   s_wpr[NCLS];       // per-class relative write pointers

    const float cix = coords[(b * NATOM + i) * 3 + 0];
    const float ciy = coords[(b * NATOM + i) * 3 + 1];
    const float ciz = coords[(b * NATOM + i) * 3 + 2];
    const int   spi = species[b * NATOM + i];

    // ---- phase 1: per-neighbor precompute (threads 0..31) + counter init ----
    if (tid < NATOM) {
        const int j = tid;
        const float x = coords[(b * NATOM + j) * 3 + 0];
        const float y = coords[(b * NATOM + j) * 3 + 1];
        const float z = coords[(b * NATOM + j) * 3 + 2];
        const float vx = x - cix, vy = y - ciy, vz = z - ciz;
        const float d2 = vx * vx + vy * vy + vz * vz;
        const float d  = sqrtf(d2 > 0.f ? d2 : 1.f);
        const int spj = species[b * NATOM + j];
        const bool ok = (j != i) && (spj >= 0) && (spi >= 0);
        const float fcA = (ok && d <= RCA_F) ? (0.5f * __cosf(d * (PI_F / RCA_F)) + 0.5f) : 0.f;
        const float fcR = (ok && d <= RCR_F) ? (0.5f * __cosf(d * (PI_F / RCR_F)) + 0.5f) : 0.f;
        svx[j] = vx; svy[j] = vy; svz[j] = vz;
        sd[j] = d; sfcA[j] = fcA; sfcR[j] = fcR;
        ssp[j] = spj < 0 ? 0 : (spj > (NSP - 1) ? (NSP - 1) : spj);
    }
    if (tid < NCLS) { s_cnt[tid] = 0; s_wpr[tid] = 0; }
    __syncthreads();

    const long obase = (long)atom * OUT_PER_ATOM;

    // ---- phase 2: radial (wave 0 only). thread = (r = tid&15, jg = tid>>4) ----
    if (tid < 64) {
        const int r  = tid & 15;
        const int jg = tid >> 4;
        const float shf = shfR[r];
        const float eta = etaR[0];
        float a0 = 0.f, a1 = 0.f, a2 = 0.f, a3 = 0.f;
        for (int j = jg; j < NATOM; j += 4) {
            const float fc = sfcR[j];
            if (fc > 0.f) {
                const float dd = sd[j] - shf;
                const float v = 0.25f * __expf(-eta * dd * dd) * fc;
                const int s = ssp[j];
                a0 += (s == 0) ? v : 0.f;
                a1 += (s == 1) ? v : 0.f;
                a2 += (s == 2) ? v : 0.f;
                a3 += (s == 3) ? v : 0.f;
            }
        }
        a0 += __shfl_xor(a0, 16); a0 += __shfl_xor(a0, 32);
        a1 += __shfl_xor(a1, 16); a1 += __shfl_xor(a1, 32);
        a2 += __shfl_xor(a2, 16); a2 += __shfl_xor(a2, 32);
        a3 += __shfl_xor(a3, 16); a3 += __shfl_xor(a3, 32);
        if (tid < 16) {
            out[obase + 0 * NSHFR + r] = a0;
            out[obase + 1 * NSHFR + r] = a1;
            out[obase + 2 * NSHFR + r] = a2;
            out[obase + 3 * NSHFR + r] = a3;
        }
    }

    // ---- phase 3A: decode pairs, count per class via LDS atomics (all waves) ----
    int   w0 = 0, w1 = 0;          // j | k<<8 | cls<<16 | act<<24
    float fac0 = 0.f, fac1 = 0.f;

#pragma unroll
    for (int cc = 0; cc < 2; ++cc) {
        const int pid = cc * 256 + tid;
        bool act = false; int j = 0, k = 0, cls = 0; float fac = 0.f;
        if (pid < NPAIRS) {
            // closed-form decode pid -> (j,k), j<k ; S(j) = 31j - j(j-1)/2
            j = (int)((63.0f - sqrtf((float)(3969 - 8 * pid))) * 0.5f);
            int Sj = j * 31 - ((j * (j - 1)) >> 1);
            if (Sj > pid) { --j; Sj = j * 31 - ((j * (j - 1)) >> 1); }
            else {
                const int Sn = (j + 1) * 31 - (((j + 1) * j) >> 1);
                if (Sn <= pid) { j += 1; Sj = Sn; }
            }
            k = j + 1 + (pid - Sj);
            fac = 2.f * sfcA[j] * sfcA[k];
            if (fac > 0.f) {
                act = true;
                const int sj = ssp[j], sk = ssp[k];
                const int lo = min(sj, sk), hi = max(sj, sk);
                cls = lo * NSP - ((lo * (lo - 1)) >> 1) + (hi - lo);
                atomicAdd(&s_cnt[cls], 1);
            }
        }
        const int w = j | (k << 8) | (cls << 16) | (act ? (1 << 24) : 0);
        if (cc == 0) { w0 = w; fac0 = fac; } else { w1 = w; fac1 = fac; }
    }
    __syncthreads();

    // ---- per-lane class offsets via predicated scan over the 10 counters ----
    const int cls0 = (w0 >> 16) & 0xff, cls1 = (w1 >> 16) & 0xff;
    int off0 = 0, off1 = 0;
#pragma unroll
    for (int q = 0; q < NCLS; ++q) {
        const int c = s_cnt[q];
        off0 += (q < cls0) ? c : 0;
        off1 += (q < cls1) ? c : 0;
    }

    // ---- phase 3B: place pairs class-sorted; precompute cs + exp factors ----
    const float eA  = etaA[0];
    const float sa0 = shfA[0], sa1 = shfA[1], sa2 = shfA[2], sa3 = shfA[3];
#pragma unroll
    for (int cc = 0; cc < 2; ++cc) {
        const int   w    = (cc == 0) ? w0 : w1;
        const float fac  = (cc == 0) ? fac0 : fac1;
        const int   offc = (cc == 0) ? off0 : off1;
        if ((w >> 24) != 0) {
            const int j = w & 0xff, k = (w >> 8) & 0xff, cls = (w >> 16) & 0xff;
            const float dj = sd[j], dk = sd[k];
            const float dot = svx[j] * svx[k] + svy[j] * svy[k] + svz[j] * svz[k];
            const float c = 0.95f * dot * __builtin_amdgcn_rcpf(fmaxf(dj * dk, 1e-10f));
            const float s = __builtin_amdgcn_sqrtf(fmaxf(1.f - c * c, 0.f));
            const float dm = 0.5f * (dj + dk);
            const float d0 = dm - sa0, d1 = dm - sa1, d2 = dm - sa2, d3 = dm - sa3;
            const float e0 = fac * __expf(-eA * d0 * d0);
            const float e1 = fac * __expf(-eA * d1 * d1);
            const float e2 = fac * __expf(-eA * d2 * d2);
            const float e3 = fac * __expf(-eA * d3 * d3);
            const int pos = offc + atomicAdd(&s_wpr[cls], 1);
            pc_cs[pos] = make_float2(0.5f * c, 0.5f * s);
            __half2* dst = reinterpret_cast<__half2*>(pc_eh + pos * 4);
            dst[0] = __floats2half2_rn(e0, e1);
            dst[1] = __floats2half2_rn(e2, e3);
        }
    }
    __syncthreads();

    // ---- phase 4: angular. 8 lane-groups own disjoint class stripes ----
    {
        const int f = tid & 31;
        const int p = f >> 3;         // ShfA index
        const int t = f & 7;          // ShfZ index
        const int stripe = tid >> 5;  // 0..7
        const int qa = (STRIPE_TAB_A >> (stripe * 4)) & 0xF;
        const int tb = (STRIPE_TAB_B >> (stripe * 4)) & 0xF;
        const int qb = (tb == 0xF) ? -1 : tb;

        int offa = 0, cnta = 0, offb = 0, cntb = 0;
#pragma unroll
        for (int q = 0; q < NCLS; ++q) {
            const int c = s_cnt[q];
            offa += (q < qa) ? c : 0;
            offb += (q < qb) ? c : 0;
            cnta = (q == qa) ? c : cnta;
            cntb = (q == qb) ? c : cntb;
        }

        float st, ct;
        __sincosf(shfZ[t], &st, &ct);
        const float zt = zeta[0];
        float* oang = out + obase + NSP * NSHFR;

        if (zt == 32.0f) {
            float acc = 0.f;
            angular_accum<true>(pc_cs, pc_eh, offa, offa + cnta, p, ct, st, zt, acc);
            oang[qa * FEAT_ANG + f] = acc;
            if (qb >= 0) {
                float accb = 0.f;
                angular_accum<true>(pc_cs, pc_eh, offb, offb + cntb, p, ct, st, zt, accb);
                oang[qb * FEAT_ANG + f] = accb;
            }
        } else {
            float acc = 0.f;
            angular_accum<false>(pc_cs, pc_eh, offa, offa + cnta, p, ct, st, zt, acc);
            oang[qa * FEAT_ANG + f] = acc;
            if (qb >= 0) {
                float accb = 0.f;
                angular_accum<false>(pc_cs, pc_eh, offb, offb + cntb, p, ct, st, zt, accb);
                oang[qb * FEAT_ANG + f] = accb;
            }
        }
    }
}

extern "C" void kernel_launch(void* const* d_in, const int* in_sizes, int n_in,
                              void* d_out, int out_size, void* d_ws, size_t ws_size,
                              hipStream_t stream) {
    const float* coords  = (const float*)d_in[0];
    const float* etaR    = (const float*)d_in[1];
    const float* shfR    = (const float*)d_in[2];
    const float* etaA    = (const float*)d_in[3];
    const float* zeta    = (const float*)d_in[4];
    const float* shfA    = (const float*)d_in[5];
    const float* shfZ    = (const float*)d_in[6];
    const int*   species = (const int*)d_in[7];
    float* out = (float*)d_out;

    const int B = in_sizes[0] / (NATOM * 3);
    aev_kernel<<<B * NATOM, 256, 0, stream>>>(coords, etaR, shfR, etaA, zeta,
                                              shfA, shfZ, species, out);
}